// Round 10
// baseline (173.640 us; speedup 1.0000x reference)
//
#include <hip/hip_runtime.h>
#include <hip/hip_bf16.h>
#include <math.h>

typedef __attribute__((ext_vector_type(8))) _Float16 half8;
typedef __attribute__((ext_vector_type(4))) float f32x4;

// ---------------- helpers ----------------

__device__ __forceinline__ float leaky02(float v) { return v > 0.0f ? v : 0.2f * v; }

__device__ __forceinline__ unsigned short f2bf(float f) {
  unsigned u = __float_as_uint(f);
  u += 0x7FFF + ((u >> 16) & 1);
  return (unsigned short)(u >> 16);
}
__device__ __forceinline__ float2 bfp(unsigned v) {
  float2 r;
  r.x = __uint_as_float(v << 16);
  r.y = __uint_as_float(v & 0xFFFF0000u);
  return r;
}

// ---------------- CSR build: 2-level bucket sort (256 dsts/bucket) ----------------

#define BSHIFT 8
#define BDSTS 256

#define CHUNK 4096
__global__ __launch_bounds__(256) void pair_scatter_kernel(
    const int* __restrict__ ei, int* __restrict__ bcursor, unsigned* __restrict__ pairs, int E) {
  __shared__ int h[256], base[256], cur[256];
  h[threadIdx.x] = 0; cur[threadIdx.x] = 0;
  __syncthreads();
  int c0 = blockIdx.x * CHUNK;
  int c1 = min(c0 + CHUNK, E);
  for (int e = c0 + (int)threadIdx.x; e < c1; e += 256)
    atomicAdd(&h[ei[E + e] >> BSHIFT], 1);
  __syncthreads();
  if (h[threadIdx.x])
    base[threadIdx.x] = atomicAdd(&bcursor[threadIdx.x], h[threadIdx.x]);
  __syncthreads();
  for (int e = c0 + (int)threadIdx.x; e < c1; e += 256) {
    int dst = ei[E + e];
    int src = ei[e];
    int b = dst >> BSHIFT;
    int r = atomicAdd(&cur[b], 1);
    pairs[base[b] + r] = ((unsigned)src << BSHIFT) | (unsigned)(dst & (BDSTS - 1));
  }
}

__global__ __launch_bounds__(256) void fine_kernel(
    const unsigned* __restrict__ pairs, const int* __restrict__ bstart,
    int* __restrict__ row_start, int* __restrict__ esrc, int N) {
  __shared__ int h[BDSTS], sc[BDSTS], cur[BDSTS];
  int t = threadIdx.x;
  int b = blockIdx.x;
  int d0 = b << BSHIFT;
  int beg = bstart[b], end = bstart[b + 1];
  h[t] = 0;
  __syncthreads();
  for (int i = beg + t; i < end; i += 256) atomicAdd(&h[pairs[i] & (BDSTS - 1)], 1);
  __syncthreads();
  int v = h[t];
  sc[t] = v;
  __syncthreads();
#pragma unroll
  for (int off = 1; off < BDSTS; off <<= 1) {
    int tmp = (t >= off) ? sc[t - off] : 0;
    __syncthreads();
    sc[t] += tmp;
    __syncthreads();
  }
  int excl = sc[t] - v;
  if (d0 + t < N) row_start[d0 + t] = beg + excl;
  cur[t] = excl;
  __syncthreads();
  for (int i = beg + t; i < end; i += 256) {
    unsigned p = pairs[i];
    int r = atomicAdd(&cur[p & (BDSTS - 1)], 1);
    esrc[beg + r] = (int)(p >> BSHIFT);
  }
}

// ---------------- W prep (fp16 transpose) + workspace zeroing ----------------

__global__ __launch_bounds__(256) void prep_w_kernel(
    const float* __restrict__ W1, const float* __restrict__ Wmu, const float* __restrict__ Wls,
    _Float16* __restrict__ Wt1, _Float16* __restrict__ Wt2,
    int* __restrict__ bcount, int* __restrict__ done, int NBUCK) {
  int idx = blockIdx.x * 256 + threadIdx.x;  // 16384 total
  int c = idx >> 7, k = idx & 127;
  Wt1[idx] = (_Float16)W1[k * 128 + c];
  float w2 = (c < 64) ? Wmu[k * 64 + c] : Wls[k * 64 + (c - 64)];
  Wt2[idx] = (_Float16)w2;
  if (blockIdx.x == 0) {
    if ((int)threadIdx.x <= NBUCK) bcount[threadIdx.x] = 0;
    if (threadIdx.x == 255) *done = 0;
  }
}

// ---------------- GEMM1 via MFMA, fused with bucket_hist + last-block scan ----------------

__global__ __launch_bounds__(256) void gemm1_hist(
    const float* __restrict__ X, const _Float16* __restrict__ Wt,
    const float* __restrict__ a_src, const float* __restrict__ a_dst,
    unsigned short* __restrict__ Hb, float* __restrict__ asrc, float* __restrict__ adst, int N,
    const int* __restrict__ ei, int* __restrict__ bcount, int E, int nGB, int nHB,
    int* __restrict__ bstart, int* __restrict__ bcursor, int* __restrict__ row_start,
    int* __restrict__ done, int NBUCK) {
  if ((int)blockIdx.x >= nGB) {
    __shared__ int h[256];
    __shared__ int lastFlag;
    h[threadIdx.x] = 0;
    __syncthreads();
    int hb = (int)blockIdx.x - nGB;
    int c0 = hb * 2048;
    int c1 = min(c0 + 2048, E);
    for (int e = c0 + (int)threadIdx.x; e < c1; e += 256)
      atomicAdd(&h[ei[E + e] >> BSHIFT], 1);
    __syncthreads();
    if (h[threadIdx.x]) atomicAdd(&bcount[threadIdx.x], h[threadIdx.x]);
    __syncthreads();
    if (threadIdx.x == 0) {
      __threadfence();
      lastFlag = (atomicAdd(done, 1) == nHB - 1) ? 1 : 0;
    }
    __syncthreads();
    if (lastFlag) {
      int t = threadIdx.x;
      int v = (t < NBUCK) ? atomicAdd(&bcount[t], 0) : 0;
      h[t] = v;
      __syncthreads();
#pragma unroll
      for (int off = 1; off < 256; off <<= 1) {
        int tmp = (t >= off) ? h[t - off] : 0;
        __syncthreads();
        h[t] += tmp;
        __syncthreads();
      }
      if (t < NBUCK) {
        int excl = h[t] - v;
        bstart[t] = excl;
        bcursor[t] = excl;
      }
      if (t == 0) { bstart[NBUCK] = E; row_start[N] = E; }
    }
    return;
  }
  const int wid = threadIdx.x >> 6, lane = threadIdx.x & 63;
  const int r16 = ((int)blockIdx.x * 4 + wid) * 16;
  if (r16 >= N) return;
  const int cg = lane & 15;
  const int kq = (lane >> 4) * 8;
  const int rowClamp = min(r16 + cg, N - 1);

  f32x4 acc[8];
#pragma unroll
  for (int j = 0; j < 8; ++j) acc[j] = (f32x4){0.f, 0.f, 0.f, 0.f};

#pragma unroll
  for (int ks = 0; ks < 4; ++ks) {
    const int k0 = ks * 32;
    const float* xp = X + (size_t)rowClamp * 128 + k0 + kq;
    float4 xa = *(const float4*)xp;
    float4 xb = *(const float4*)(xp + 4);
    half8 a;
    a[0] = (_Float16)xa.x; a[1] = (_Float16)xa.y; a[2] = (_Float16)xa.z; a[3] = (_Float16)xa.w;
    a[4] = (_Float16)xb.x; a[5] = (_Float16)xb.y; a[6] = (_Float16)xb.z; a[7] = (_Float16)xb.w;
#pragma unroll
    for (int j = 0; j < 8; ++j) {
      half8 b = *(const half8*)(Wt + (size_t)(16 * j + cg) * 128 + k0 + kq);
      acc[j] = __builtin_amdgcn_mfma_f32_16x16x32_f16(a, b, acc[j], 0, 0, 0);
    }
  }

  float as_[8], ds_[8];
#pragma unroll
  for (int j = 0; j < 8; ++j) { as_[j] = a_src[16 * j + cg]; ds_[j] = a_dst[16 * j + cg]; }
  const int rg = (lane >> 4) * 4;
#pragma unroll
  for (int reg = 0; reg < 4; ++reg) {
    int row = r16 + rg + reg;
    bool ok = row < N;
    float ps = 0.f, pd = 0.f;
#pragma unroll
    for (int j = 0; j < 8; ++j) {
      float v = acc[j][reg];
      if (ok) Hb[(size_t)row * 128 + 16 * j + cg] = f2bf(v);
      ps = fmaf(v, as_[j], ps);
      pd = fmaf(v, ds_[j], pd);
    }
#pragma unroll
    for (int o = 1; o < 16; o <<= 1) { ps += __shfl_xor(ps, o); pd += __shfl_xor(pd, o); }
    if (ok && cg == 0) { asrc[row] = ps; adst[row] = pd; }
  }
}

__global__ __launch_bounds__(256) void gemm2_mfma(
    const _Float16* __restrict__ Xh, const _Float16* __restrict__ Wt,
    const float* __restrict__ a_src_mu, const float* __restrict__ a_dst_mu,
    const float* __restrict__ a_src_ls, const float* __restrict__ a_dst_ls,
    unsigned short* __restrict__ Hb, float* __restrict__ as2, float* __restrict__ ad2, int N) {
  const int wid = threadIdx.x >> 6, lane = threadIdx.x & 63;
  const int r16 = ((int)blockIdx.x * 4 + wid) * 16;
  if (r16 >= N) return;
  const int cg = lane & 15;
  const int kq = (lane >> 4) * 8;
  const int rowClamp = min(r16 + cg, N - 1);

  f32x4 acc[8];
#pragma unroll
  for (int j = 0; j < 8; ++j) acc[j] = (f32x4){0.f, 0.f, 0.f, 0.f};

#pragma unroll
  for (int ks = 0; ks < 4; ++ks) {
    const int k0 = ks * 32;
    half8 a = *(const half8*)(Xh + (size_t)rowClamp * 128 + k0 + kq);
#pragma unroll
    for (int j = 0; j < 8; ++j) {
      half8 b = *(const half8*)(Wt + (size_t)(16 * j + cg) * 128 + k0 + kq);
      acc[j] = __builtin_amdgcn_mfma_f32_16x16x32_f16(a, b, acc[j], 0, 0, 0);
    }
  }

  float asv[8], adv[8];
#pragma unroll
  for (int j = 0; j < 4; ++j) {
    asv[j] = a_src_mu[16 * j + cg]; adv[j] = a_dst_mu[16 * j + cg];
    asv[j + 4] = a_src_ls[16 * j + cg]; adv[j + 4] = a_dst_ls[16 * j + cg];
  }
  const int rg = (lane >> 4) * 4;
#pragma unroll
  for (int reg = 0; reg < 4; ++reg) {
    int row = r16 + rg + reg;
    bool ok = row < N;
    float psm = 0.f, pdm = 0.f, psl = 0.f, pdl = 0.f;
#pragma unroll
    for (int j = 0; j < 8; ++j) {
      float v = acc[j][reg];
      if (ok) Hb[(size_t)row * 128 + 16 * j + cg] = f2bf(v);
      if (j < 4) { psm = fmaf(v, asv[j], psm); pdm = fmaf(v, adv[j], pdm); }
      else       { psl = fmaf(v, asv[j], psl); pdl = fmaf(v, adv[j], pdl); }
    }
#pragma unroll
    for (int o = 1; o < 16; o <<= 1) {
      psm += __shfl_xor(psm, o); pdm += __shfl_xor(pdm, o);
      psl += __shfl_xor(psl, o); pdl += __shfl_xor(pdl, o);
    }
    if (ok && cg == 0) {
      as2[2 * row] = psm; ad2[2 * row] = pdm;
      as2[2 * row + 1] = psl; ad2[2 * row + 1] = pdl;
    }
  }
}

// ---------------- Aggregation layer 1: max-MLP (all chunk gathers in flight) ----------------
// wave = 2 dsts (half = lane>>5); per half, 2 groups of 16 lanes; lane li owns 8 channels.
// Per 32-edge chunk: issue up to 16 predicated uint4 gathers per group, then FMA pass.

__global__ __launch_bounds__(256) void agg1_mlp(
    const unsigned short* __restrict__ Hb, const float* __restrict__ asrc,
    const float* __restrict__ adst, const int* __restrict__ row_start,
    const int* __restrict__ esrc, const float* __restrict__ b,
    _Float16* __restrict__ hout, int N) {
  const int lane = threadIdx.x & 63;
  const int half = lane >> 5, sub = lane & 31;
  const int grp = (lane >> 4) & 1, li = lane & 15;
  const int g = (int)(blockIdx.x * 4 + (threadIdx.x >> 6));
  const int d = g * 2 + half;
  const bool dok = d < N;
  const int dc = dok ? d : N - 1;
  const float ad = adst[dc];
  const float wself = __expf(leaky02(asrc[dc] + ad));
  float a0 = 0.f, a1 = 0.f, a2 = 0.f, a3 = 0.f, a4 = 0.f, a5 = 0.f, a6 = 0.f, a7 = 0.f;
  if (grp == 0) {
    uint4 sv = *(const uint4*)(Hb + (size_t)dc * 128 + li * 8);
    float2 q0 = bfp(sv.x), q1 = bfp(sv.y), q2 = bfp(sv.z), q3 = bfp(sv.w);
    a0 = wself * q0.x; a1 = wself * q0.y; a2 = wself * q1.x; a3 = wself * q1.y;
    a4 = wself * q2.x; a5 = wself * q2.y; a6 = wself * q3.x; a7 = wself * q3.y;
  }
  float den = (sub == 0) ? wself : 0.f;
  const int beg = row_start[dc];
  const int n = dok ? (row_start[dc + 1] - beg) : 0;
  const int nmax = max(n, __shfl_xor(n, 32));
  const int hbase = half * 32;
  for (int c0 = 0; c0 < nmax; c0 += 32) {
    int j = c0 + sub;
    bool v = j < n;
    int s = v ? esrc[beg + j] : 0;
    float w = v ? __expf(leaky02(asrc[s] + ad)) : 0.f;
    den += w;
    int cnt = min(max(n - c0, 0), 32);
    float wA[16];
    uint4 rg[16];
#pragma unroll
    for (int t = 0; t < 16; ++t) {
      int idx = 2 * t + grp;
      int sA = __shfl(s, hbase + idx);
      wA[t] = __shfl(w, hbase + idx);
      if (idx < cnt) rg[t] = *(const uint4*)(Hb + (size_t)sA * 128 + li * 8);
    }
#pragma unroll
    for (int t = 0; t < 16; ++t) {
      int idx = 2 * t + grp;
      if (idx < cnt) {
        float2 q0 = bfp(rg[t].x), q1 = bfp(rg[t].y), q2 = bfp(rg[t].z), q3 = bfp(rg[t].w);
        float wt = wA[t];
        a0 = fmaf(wt, q0.x, a0); a1 = fmaf(wt, q0.y, a1);
        a2 = fmaf(wt, q1.x, a2); a3 = fmaf(wt, q1.y, a3);
        a4 = fmaf(wt, q2.x, a4); a5 = fmaf(wt, q2.y, a5);
        a6 = fmaf(wt, q3.x, a6); a7 = fmaf(wt, q3.y, a7);
      }
    }
  }
  a0 += __shfl_xor(a0, 16); a1 += __shfl_xor(a1, 16);
  a2 += __shfl_xor(a2, 16); a3 += __shfl_xor(a3, 16);
  a4 += __shfl_xor(a4, 16); a5 += __shfl_xor(a5, 16);
  a6 += __shfl_xor(a6, 16); a7 += __shfl_xor(a7, 16);
#pragma unroll
  for (int o = 16; o > 0; o >>= 1) den += __shfl_xor(den, o);
  if (dok && grp == 0) {
    float inv = 1.0f / den;
    float4 b0 = *(const float4*)(b + li * 8);
    float4 b1 = *(const float4*)(b + li * 8 + 4);
    _Float16 o8[8];
    o8[0] = (_Float16)fmaxf(fmaf(a0, inv, b0.x), 0.f);
    o8[1] = (_Float16)fmaxf(fmaf(a1, inv, b0.y), 0.f);
    o8[2] = (_Float16)fmaxf(fmaf(a2, inv, b0.z), 0.f);
    o8[3] = (_Float16)fmaxf(fmaf(a3, inv, b0.w), 0.f);
    o8[4] = (_Float16)fmaxf(fmaf(a4, inv, b1.x), 0.f);
    o8[5] = (_Float16)fmaxf(fmaf(a5, inv, b1.y), 0.f);
    o8[6] = (_Float16)fmaxf(fmaf(a6, inv, b1.z), 0.f);
    o8[7] = (_Float16)fmaxf(fmaf(a7, inv, b1.w), 0.f);
    *(uint4*)(hout + (size_t)d * 128 + li * 8) = *(uint4*)o8;
  }
}

// ---------------- Aggregation layers 2+3 fused: max-MLP ----------------
// lane li<8 -> mu channels li*8..+7; li>=8 -> ls channels (li-8)*8..+7.

__global__ __launch_bounds__(256) void agg2_mlp(
    const unsigned short* __restrict__ Hb,
    const float2* __restrict__ as2, const float2* __restrict__ ad2,
    const int* __restrict__ row_start, const int* __restrict__ esrc,
    const float* __restrict__ b_mu, const float* __restrict__ b_ls,
    float* __restrict__ out_mu, float* __restrict__ out_ls, int N) {
  const int lane = threadIdx.x & 63;
  const int half = lane >> 5, sub = lane & 31;
  const int grp = (lane >> 4) & 1, li = lane & 15;
  const bool isMu = li < 8;
  const int g = (int)(blockIdx.x * 4 + (threadIdx.x >> 6));
  const int d = g * 2 + half;
  const bool dok = d < N;
  const int dc = dok ? d : N - 1;
  const float2 adv = ad2[dc];
  const float2 asv = as2[dc];
  const float wself_m = __expf(leaky02(asv.x + adv.x));
  const float wself_l = __expf(leaky02(asv.y + adv.y));
  float a0 = 0.f, a1 = 0.f, a2 = 0.f, a3 = 0.f, a4 = 0.f, a5 = 0.f, a6 = 0.f, a7 = 0.f;
  if (grp == 0) {
    const float wself = isMu ? wself_m : wself_l;
    uint4 sv = *(const uint4*)(Hb + (size_t)dc * 128 + li * 8);
    float2 q0 = bfp(sv.x), q1 = bfp(sv.y), q2 = bfp(sv.z), q3 = bfp(sv.w);
    a0 = wself * q0.x; a1 = wself * q0.y; a2 = wself * q1.x; a3 = wself * q1.y;
    a4 = wself * q2.x; a5 = wself * q2.y; a6 = wself * q3.x; a7 = wself * q3.y;
  }
  float den_m = (sub == 0) ? wself_m : 0.f;
  float den_l = (sub == 0) ? wself_l : 0.f;
  const int beg = row_start[dc];
  const int n = dok ? (row_start[dc + 1] - beg) : 0;
  const int nmax = max(n, __shfl_xor(n, 32));
  const int hbase = half * 32;
  for (int c0 = 0; c0 < nmax; c0 += 32) {
    int j = c0 + sub;
    bool v = j < n;
    int s = v ? esrc[beg + j] : 0;
    float wm = 0.f, wl = 0.f;
    if (v) {
      float2 av = as2[s];
      wm = __expf(leaky02(av.x + adv.x));
      wl = __expf(leaky02(av.y + adv.y));
    }
    den_m += wm;
    den_l += wl;
    int cnt = min(max(n - c0, 0), 32);
    float wA[16];
    uint4 rg[16];
#pragma unroll
    for (int t = 0; t < 16; ++t) {
      int idx = 2 * t + grp;
      int sA = __shfl(s, hbase + idx);
      float wmA = __shfl(wm, hbase + idx);
      float wlA = __shfl(wl, hbase + idx);
      wA[t] = isMu ? wmA : wlA;
      if (idx < cnt) rg[t] = *(const uint4*)(Hb + (size_t)sA * 128 + li * 8);
    }
#pragma unroll
    for (int t = 0; t < 16; ++t) {
      int idx = 2 * t + grp;
      if (idx < cnt) {
        float2 q0 = bfp(rg[t].x), q1 = bfp(rg[t].y), q2 = bfp(rg[t].z), q3 = bfp(rg[t].w);
        float wt = wA[t];
        a0 = fmaf(wt, q0.x, a0); a1 = fmaf(wt, q0.y, a1);
        a2 = fmaf(wt, q1.x, a2); a3 = fmaf(wt, q1.y, a3);
        a4 = fmaf(wt, q2.x, a4); a5 = fmaf(wt, q2.y, a5);
        a6 = fmaf(wt, q3.x, a6); a7 = fmaf(wt, q3.y, a7);
      }
    }
  }
  a0 += __shfl_xor(a0, 16); a1 += __shfl_xor(a1, 16);
  a2 += __shfl_xor(a2, 16); a3 += __shfl_xor(a3, 16);
  a4 += __shfl_xor(a4, 16); a5 += __shfl_xor(a5, 16);
  a6 += __shfl_xor(a6, 16); a7 += __shfl_xor(a7, 16);
#pragma unroll
  for (int o = 16; o > 0; o >>= 1) {
    den_m += __shfl_xor(den_m, o);
    den_l += __shfl_xor(den_l, o);
  }
  if (dok && grp == 0) {
    float inv = isMu ? (1.0f / den_m) : (1.0f / den_l);
    const float* bp;
    float* op;
    if (isMu) { bp = b_mu + li * 8; op = out_mu + (size_t)d * 64 + li * 8; }
    else      { bp = b_ls + (li - 8) * 8; op = out_ls + (size_t)d * 64 + (li - 8) * 8; }
    float4 b0 = *(const float4*)bp;
    float4 b1 = *(const float4*)(bp + 4);
    float4 o0, o1;
    o0.x = fmaf(a0, inv, b0.x); o0.y = fmaf(a1, inv, b0.y);
    o0.z = fmaf(a2, inv, b0.z); o0.w = fmaf(a3, inv, b0.w);
    o1.x = fmaf(a4, inv, b1.x); o1.y = fmaf(a5, inv, b1.y);
    o1.z = fmaf(a6, inv, b1.z); o1.w = fmaf(a7, inv, b1.w);
    *(float4*)op = o0;
    *(float4*)(op + 4) = o1;
  }
}

// ---------------- launch ----------------

extern "C" void kernel_launch(void* const* d_in, const int* in_sizes, int n_in,
                              void* d_out, int out_size, void* d_ws, size_t ws_size,
                              hipStream_t stream) {
  const float* x = (const float*)d_in[0];
  const int* ei = (const int*)d_in[1];
  const float* W1 = (const float*)d_in[2];
  const float* a_src1 = (const float*)d_in[3];
  const float* a_dst1 = (const float*)d_in[4];
  const float* b1 = (const float*)d_in[5];
  const float* W_mu = (const float*)d_in[6];
  const float* a_src_mu = (const float*)d_in[7];
  const float* a_dst_mu = (const float*)d_in[8];
  const float* b_mu = (const float*)d_in[9];
  const float* W_ls = (const float*)d_in[10];
  const float* a_src_ls = (const float*)d_in[11];
  const float* a_dst_ls = (const float*)d_in[12];
  const float* b_ls = (const float*)d_in[13];

  const int N = in_sizes[0] / 128;  // 50000
  const int E = in_sizes[1] / 2;    // 800000
  const int NBUCK = (N + BDSTS - 1) >> BSHIFT;  // 196 (<=256)

  uint8_t* p = (uint8_t*)d_ws;
  auto carve = [&](size_t bytes) -> void* {
    void* q = (void*)p;
    p += (bytes + 255) & ~(size_t)255;
    return q;
  };
  int* bcount = (int*)carve((size_t)(NBUCK + 1) * 4);
  int* bstart = (int*)carve((size_t)(NBUCK + 1) * 4);
  int* bcursor = (int*)carve((size_t)NBUCK * 4);
  int* done = (int*)carve(4);
  int* row_start = (int*)carve((size_t)(N + 1) * 4);
  int* esrc = (int*)carve((size_t)E * 4);
  unsigned* pairs = (unsigned*)carve((size_t)E * 4);
  unsigned short* Hb1 = (unsigned short*)carve((size_t)N * 128 * 2);  // bf16; reused as Hb2
  _Float16* h1 = (_Float16*)carve((size_t)N * 128 * 2);               // fp16 gemm2 input
  _Float16* Wt1 = (_Float16*)carve((size_t)128 * 128 * 2);
  _Float16* Wt2 = (_Float16*)carve((size_t)128 * 128 * 2);
  float* as1 = (float*)carve((size_t)N * 4);
  float* ad1 = (float*)carve((size_t)N * 4);
  float* as2 = (float*)carve((size_t)N * 8);
  float* ad2 = (float*)carve((size_t)N * 8);

  unsigned short* Hb2 = Hb1;

  prep_w_kernel<<<64, 256, 0, stream>>>(W1, W_mu, W_ls, Wt1, Wt2, bcount, done, NBUCK);

  const int nGB = (N + 63) / 64;          // gemm1 blocks
  const int nHB = (E + 2047) / 2048;      // hist blocks
  gemm1_hist<<<nGB + nHB, 256, 0, stream>>>(x, Wt1, a_src1, a_dst1, Hb1, as1, ad1, N,
                                            ei, bcount, E, nGB, nHB,
                                            bstart, bcursor, row_start, done, NBUCK);
  pair_scatter_kernel<<<(E + CHUNK - 1) / CHUNK, 256, 0, stream>>>(ei, bcursor, pairs, E);
  fine_kernel<<<NBUCK, 256, 0, stream>>>(pairs, bstart, row_start, esrc, N);

  const int nwaves = (N + 1) / 2;
  const int nblk = (nwaves + 3) / 4;
  agg1_mlp<<<nblk, 256, 0, stream>>>(Hb1, as1, ad1, row_start, esrc, b1, h1, N);
  gemm2_mfma<<<(N + 63) / 64, 256, 0, stream>>>(h1, Wt2, a_src_mu, a_dst_mu,
                                                a_src_ls, a_dst_ls, Hb2, as2, ad2, N);
  float* out_mu = (float*)d_out;
  float* out_ls = out_mu + (size_t)N * 64;
  agg2_mlp<<<nblk, 256, 0, stream>>>(Hb2, (const float2*)as2, (const float2*)ad2,
                                     row_start, esrc, b_mu, b_ls, out_mu, out_ls, N);
}

// Round 11
// 155.882 us; speedup vs baseline: 1.1139x; 1.1139x over previous
//
#include <hip/hip_runtime.h>
#include <hip/hip_bf16.h>
#include <math.h>

typedef __attribute__((ext_vector_type(8))) _Float16 half8;
typedef __attribute__((ext_vector_type(4))) float f32x4;

// ---------------- helpers ----------------

__device__ __forceinline__ float leaky02(float v) { return v > 0.0f ? v : 0.2f * v; }

__device__ __forceinline__ unsigned short f2bf(float f) {
  unsigned u = __float_as_uint(f);
  u += 0x7FFF + ((u >> 16) & 1);
  return (unsigned short)(u >> 16);
}
__device__ __forceinline__ float2 bfp(unsigned v) {
  float2 r;
  r.x = __uint_as_float(v << 16);
  r.y = __uint_as_float(v & 0xFFFF0000u);
  return r;
}

#define BSHIFT 8
#define BDSTS 256
#define CHUNK 4096

// ---------------- K1: W prep || bucket hist || elected bucket-scan ----------------
// blocks [0,nPB): fp16 weight transpose; blocks [nPB,nPB+nHB): dst-bucket histogram;
// the last hist block to finish scans bcount -> bstart/bcursor.

__global__ __launch_bounds__(256) void prep_hist(
    const float* __restrict__ W1, const float* __restrict__ Wmu, const float* __restrict__ Wls,
    _Float16* __restrict__ Wt1, _Float16* __restrict__ Wt2,
    const int* __restrict__ ei, int* __restrict__ bcount, int E, int nPB, int nHB,
    int* __restrict__ bstart, int* __restrict__ bcursor, int* __restrict__ row_start,
    int* __restrict__ done, int NBUCK, int N) {
  if ((int)blockIdx.x < nPB) {
    int idx = blockIdx.x * 256 + threadIdx.x;  // 16384 total
    int c = idx >> 7, k = idx & 127;
    Wt1[idx] = (_Float16)W1[k * 128 + c];
    float w2 = (c < 64) ? Wmu[k * 64 + c] : Wls[k * 64 + (c - 64)];
    Wt2[idx] = (_Float16)w2;
    return;
  }
  __shared__ int h[256];
  __shared__ int lastFlag;
  h[threadIdx.x] = 0;
  __syncthreads();
  int hb = (int)blockIdx.x - nPB;
  int c0 = hb * 2048;
  int c1 = min(c0 + 2048, E);
  for (int e = c0 + (int)threadIdx.x; e < c1; e += 256)
    atomicAdd(&h[ei[E + e] >> BSHIFT], 1);
  __syncthreads();
  if (h[threadIdx.x]) atomicAdd(&bcount[threadIdx.x], h[threadIdx.x]);
  __syncthreads();
  if (threadIdx.x == 0) {
    __threadfence();
    lastFlag = (atomicAdd(done, 1) == nHB - 1) ? 1 : 0;
  }
  __syncthreads();
  if (lastFlag) {
    int t = threadIdx.x;
    int v = (t < NBUCK) ? atomicAdd(&bcount[t], 0) : 0;
    h[t] = v;
    __syncthreads();
#pragma unroll
    for (int off = 1; off < 256; off <<= 1) {
      int tmp = (t >= off) ? h[t - off] : 0;
      __syncthreads();
      h[t] += tmp;
      __syncthreads();
    }
    if (t < NBUCK) {
      int excl = h[t] - v;
      bstart[t] = excl;
      bcursor[t] = excl;
    }
    if (t == 0) { bstart[NBUCK] = E; row_start[N] = E; }
  }
}

// ---------------- K2: GEMM1 (MFMA) || pair scatter ----------------
// blocks [0,nGB): gemm1; blocks [nGB, nGB+nSC): bucketed pair scatter.

__global__ __launch_bounds__(256) void gemm1_scatter(
    const float* __restrict__ X, const _Float16* __restrict__ Wt,
    const float* __restrict__ a_src, const float* __restrict__ a_dst,
    unsigned short* __restrict__ Hb, float* __restrict__ asrc, float* __restrict__ adst, int N,
    const int* __restrict__ ei, int* __restrict__ bcursor, unsigned* __restrict__ pairs,
    int E, int nGB) {
  if ((int)blockIdx.x >= nGB) {
    __shared__ int h[256], base[256], cur[256];
    h[threadIdx.x] = 0; cur[threadIdx.x] = 0;
    __syncthreads();
    int sb = (int)blockIdx.x - nGB;
    int c0 = sb * CHUNK;
    int c1 = min(c0 + CHUNK, E);
    for (int e = c0 + (int)threadIdx.x; e < c1; e += 256)
      atomicAdd(&h[ei[E + e] >> BSHIFT], 1);
    __syncthreads();
    if (h[threadIdx.x])
      base[threadIdx.x] = atomicAdd(&bcursor[threadIdx.x], h[threadIdx.x]);
    __syncthreads();
    for (int e = c0 + (int)threadIdx.x; e < c1; e += 256) {
      int dst = ei[E + e];
      int src = ei[e];
      int b = dst >> BSHIFT;
      int r = atomicAdd(&cur[b], 1);
      pairs[base[b] + r] = ((unsigned)src << BSHIFT) | (unsigned)(dst & (BDSTS - 1));
    }
    return;
  }
  const int wid = threadIdx.x >> 6, lane = threadIdx.x & 63;
  const int r16 = ((int)blockIdx.x * 4 + wid) * 16;
  if (r16 >= N) return;
  const int cg = lane & 15;
  const int kq = (lane >> 4) * 8;
  const int rowClamp = min(r16 + cg, N - 1);

  f32x4 acc[8];
#pragma unroll
  for (int j = 0; j < 8; ++j) acc[j] = (f32x4){0.f, 0.f, 0.f, 0.f};

#pragma unroll
  for (int ks = 0; ks < 4; ++ks) {
    const int k0 = ks * 32;
    const float* xp = X + (size_t)rowClamp * 128 + k0 + kq;
    float4 xa = *(const float4*)xp;
    float4 xb = *(const float4*)(xp + 4);
    half8 a;
    a[0] = (_Float16)xa.x; a[1] = (_Float16)xa.y; a[2] = (_Float16)xa.z; a[3] = (_Float16)xa.w;
    a[4] = (_Float16)xb.x; a[5] = (_Float16)xb.y; a[6] = (_Float16)xb.z; a[7] = (_Float16)xb.w;
#pragma unroll
    for (int j = 0; j < 8; ++j) {
      half8 b = *(const half8*)(Wt + (size_t)(16 * j + cg) * 128 + k0 + kq);
      acc[j] = __builtin_amdgcn_mfma_f32_16x16x32_f16(a, b, acc[j], 0, 0, 0);
    }
  }

  float as_[8], ds_[8];
#pragma unroll
  for (int j = 0; j < 8; ++j) { as_[j] = a_src[16 * j + cg]; ds_[j] = a_dst[16 * j + cg]; }
  const int rg = (lane >> 4) * 4;
#pragma unroll
  for (int reg = 0; reg < 4; ++reg) {
    int row = r16 + rg + reg;
    bool ok = row < N;
    float ps = 0.f, pd = 0.f;
#pragma unroll
    for (int j = 0; j < 8; ++j) {
      float v = acc[j][reg];
      if (ok) Hb[(size_t)row * 128 + 16 * j + cg] = f2bf(v);
      ps = fmaf(v, as_[j], ps);
      pd = fmaf(v, ds_[j], pd);
    }
#pragma unroll
    for (int o = 1; o < 16; o <<= 1) { ps += __shfl_xor(ps, o); pd += __shfl_xor(pd, o); }
    if (ok && cg == 0) { asrc[row] = ps; adst[row] = pd; }
  }
}

// ---------------- fine: per-bucket dst ranking -> row_start + esrc ----------------

__global__ __launch_bounds__(256) void fine_kernel(
    const unsigned* __restrict__ pairs, const int* __restrict__ bstart,
    int* __restrict__ row_start, int* __restrict__ esrc, int N) {
  __shared__ int h[BDSTS], sc[BDSTS], cur[BDSTS];
  int t = threadIdx.x;
  int b = blockIdx.x;
  int d0 = b << BSHIFT;
  int beg = bstart[b], end = bstart[b + 1];
  h[t] = 0;
  __syncthreads();
  for (int i = beg + t; i < end; i += 256) atomicAdd(&h[pairs[i] & (BDSTS - 1)], 1);
  __syncthreads();
  int v = h[t];
  sc[t] = v;
  __syncthreads();
#pragma unroll
  for (int off = 1; off < BDSTS; off <<= 1) {
    int tmp = (t >= off) ? sc[t - off] : 0;
    __syncthreads();
    sc[t] += tmp;
    __syncthreads();
  }
  int excl = sc[t] - v;
  if (d0 + t < N) row_start[d0 + t] = beg + excl;
  cur[t] = excl;
  __syncthreads();
  for (int i = beg + t; i < end; i += 256) {
    unsigned p = pairs[i];
    int r = atomicAdd(&cur[p & (BDSTS - 1)], 1);
    esrc[beg + r] = (int)(p >> BSHIFT);
  }
}

// ---------------- GEMM2 via MFMA ----------------

__global__ __launch_bounds__(256) void gemm2_mfma(
    const _Float16* __restrict__ Xh, const _Float16* __restrict__ Wt,
    const float* __restrict__ a_src_mu, const float* __restrict__ a_dst_mu,
    const float* __restrict__ a_src_ls, const float* __restrict__ a_dst_ls,
    unsigned short* __restrict__ Hb, float* __restrict__ as2, float* __restrict__ ad2, int N) {
  const int wid = threadIdx.x >> 6, lane = threadIdx.x & 63;
  const int r16 = ((int)blockIdx.x * 4 + wid) * 16;
  if (r16 >= N) return;
  const int cg = lane & 15;
  const int kq = (lane >> 4) * 8;
  const int rowClamp = min(r16 + cg, N - 1);

  f32x4 acc[8];
#pragma unroll
  for (int j = 0; j < 8; ++j) acc[j] = (f32x4){0.f, 0.f, 0.f, 0.f};

#pragma unroll
  for (int ks = 0; ks < 4; ++ks) {
    const int k0 = ks * 32;
    half8 a = *(const half8*)(Xh + (size_t)rowClamp * 128 + k0 + kq);
#pragma unroll
    for (int j = 0; j < 8; ++j) {
      half8 b = *(const half8*)(Wt + (size_t)(16 * j + cg) * 128 + k0 + kq);
      acc[j] = __builtin_amdgcn_mfma_f32_16x16x32_f16(a, b, acc[j], 0, 0, 0);
    }
  }

  float asv[8], adv[8];
#pragma unroll
  for (int j = 0; j < 4; ++j) {
    asv[j] = a_src_mu[16 * j + cg]; adv[j] = a_dst_mu[16 * j + cg];
    asv[j + 4] = a_src_ls[16 * j + cg]; adv[j + 4] = a_dst_ls[16 * j + cg];
  }
  const int rg = (lane >> 4) * 4;
#pragma unroll
  for (int reg = 0; reg < 4; ++reg) {
    int row = r16 + rg + reg;
    bool ok = row < N;
    float psm = 0.f, pdm = 0.f, psl = 0.f, pdl = 0.f;
#pragma unroll
    for (int j = 0; j < 8; ++j) {
      float v = acc[j][reg];
      if (ok) Hb[(size_t)row * 128 + 16 * j + cg] = f2bf(v);
      if (j < 4) { psm = fmaf(v, asv[j], psm); pdm = fmaf(v, adv[j], pdm); }
      else       { psl = fmaf(v, asv[j], psl); pdl = fmaf(v, adv[j], pdl); }
    }
#pragma unroll
    for (int o = 1; o < 16; o <<= 1) {
      psm += __shfl_xor(psm, o); pdm += __shfl_xor(pdm, o);
      psl += __shfl_xor(psl, o); pdl += __shfl_xor(pdl, o);
    }
    if (ok && cg == 0) {
      as2[2 * row] = psm; ad2[2 * row] = pdm;
      as2[2 * row + 1] = psl; ad2[2 * row + 1] = pdl;
    }
  }
}

// ---------------- Aggregation layer 1: 16-lane groups, 16B gathers (round-9 best) ----------------

#define STEP1(J)                                                          \
  {                                                                       \
    int idx = (J) + grp;                                                  \
    int sA = __shfl(s, hbase + idx);                                      \
    float wA = __shfl(w, hbase + idx);                                    \
    uint4 hv = *(const uint4*)(Hb + (size_t)sA * 128 + li * 8);           \
    float2 q0 = bfp(hv.x), q1 = bfp(hv.y), q2 = bfp(hv.z), q3 = bfp(hv.w);\
    a0 = fmaf(wA, q0.x, a0); a1 = fmaf(wA, q0.y, a1);                     \
    a2 = fmaf(wA, q1.x, a2); a3 = fmaf(wA, q1.y, a3);                     \
    a4 = fmaf(wA, q2.x, a4); a5 = fmaf(wA, q2.y, a5);                     \
    a6 = fmaf(wA, q3.x, a6); a7 = fmaf(wA, q3.y, a7);                     \
  }

__global__ __launch_bounds__(256) void agg1_g16(
    const unsigned short* __restrict__ Hb, const float* __restrict__ asrc,
    const float* __restrict__ adst, const int* __restrict__ row_start,
    const int* __restrict__ esrc, const float* __restrict__ b,
    _Float16* __restrict__ hout, int N) {
  const int lane = threadIdx.x & 63;
  const int half = lane >> 5, sub = lane & 31;
  const int grp = (lane >> 4) & 1, li = lane & 15;
  const int g = (int)(blockIdx.x * 4 + (threadIdx.x >> 6));
  const int d = g * 2 + half;
  const bool dok = d < N;
  const int dc = dok ? d : N - 1;
  const float ad = adst[dc];
  const float wself = __expf(leaky02(asrc[dc] + ad));
  float a0 = 0.f, a1 = 0.f, a2 = 0.f, a3 = 0.f, a4 = 0.f, a5 = 0.f, a6 = 0.f, a7 = 0.f;
  if (grp == 0) {
    uint4 sv = *(const uint4*)(Hb + (size_t)dc * 128 + li * 8);
    float2 q0 = bfp(sv.x), q1 = bfp(sv.y), q2 = bfp(sv.z), q3 = bfp(sv.w);
    a0 = wself * q0.x; a1 = wself * q0.y; a2 = wself * q1.x; a3 = wself * q1.y;
    a4 = wself * q2.x; a5 = wself * q2.y; a6 = wself * q3.x; a7 = wself * q3.y;
  }
  float den = (sub == 0) ? wself : 0.f;
  const int beg = row_start[dc];
  const int n = dok ? (row_start[dc + 1] - beg) : 0;
  const int nmax = max(n, __shfl_xor(n, 32));
  const int hbase = half * 32;
  for (int c0 = 0; c0 < nmax; c0 += 32) {
    int j = c0 + sub;
    bool v = j < n;
    int s = v ? esrc[beg + j] : 0;
    float w = v ? __expf(leaky02(asrc[s] + ad)) : 0.f;
    den += w;
    int cnt = min(max(n - c0, 0), 32);
    int jj = 0;
    for (; jj + 8 <= cnt; jj += 8) { STEP1(jj) STEP1(jj + 2) STEP1(jj + 4) STEP1(jj + 6) }
    for (; jj < cnt; jj += 2) {
      int idx = jj + grp;
      int sA = __shfl(s, hbase + idx);
      float wA = __shfl(w, hbase + idx);
      if (idx < cnt) {
        uint4 hv = *(const uint4*)(Hb + (size_t)sA * 128 + li * 8);
        float2 q0 = bfp(hv.x), q1 = bfp(hv.y), q2 = bfp(hv.z), q3 = bfp(hv.w);
        a0 = fmaf(wA, q0.x, a0); a1 = fmaf(wA, q0.y, a1);
        a2 = fmaf(wA, q1.x, a2); a3 = fmaf(wA, q1.y, a3);
        a4 = fmaf(wA, q2.x, a4); a5 = fmaf(wA, q2.y, a5);
        a6 = fmaf(wA, q3.x, a6); a7 = fmaf(wA, q3.y, a7);
      }
    }
  }
  a0 += __shfl_xor(a0, 16); a1 += __shfl_xor(a1, 16);
  a2 += __shfl_xor(a2, 16); a3 += __shfl_xor(a3, 16);
  a4 += __shfl_xor(a4, 16); a5 += __shfl_xor(a5, 16);
  a6 += __shfl_xor(a6, 16); a7 += __shfl_xor(a7, 16);
#pragma unroll
  for (int o = 16; o > 0; o >>= 1) den += __shfl_xor(den, o);
  if (dok && grp == 0) {
    float inv = 1.0f / den;
    float4 b0 = *(const float4*)(b + li * 8);
    float4 b1 = *(const float4*)(b + li * 8 + 4);
    _Float16 o8[8];
    o8[0] = (_Float16)fmaxf(fmaf(a0, inv, b0.x), 0.f);
    o8[1] = (_Float16)fmaxf(fmaf(a1, inv, b0.y), 0.f);
    o8[2] = (_Float16)fmaxf(fmaf(a2, inv, b0.z), 0.f);
    o8[3] = (_Float16)fmaxf(fmaf(a3, inv, b0.w), 0.f);
    o8[4] = (_Float16)fmaxf(fmaf(a4, inv, b1.x), 0.f);
    o8[5] = (_Float16)fmaxf(fmaf(a5, inv, b1.y), 0.f);
    o8[6] = (_Float16)fmaxf(fmaf(a6, inv, b1.z), 0.f);
    o8[7] = (_Float16)fmaxf(fmaf(a7, inv, b1.w), 0.f);
    *(uint4*)(hout + (size_t)d * 128 + li * 8) = *(uint4*)o8;
  }
}

// ---------------- Aggregation layers 2+3 fused: 16-lane groups (round-9 best) ----------------

#define STEP2(J)                                                          \
  {                                                                       \
    int idx = (J) + grp;                                                  \
    int sA = __shfl(s, hbase + idx);                                      \
    float wmA = __shfl(wm, hbase + idx);                                  \
    float wlA = __shfl(wl, hbase + idx);                                  \
    float wA = isMu ? wmA : wlA;                                          \
    uint4 hv = *(const uint4*)(Hb + (size_t)sA * 128 + li * 8);           \
    float2 q0 = bfp(hv.x), q1 = bfp(hv.y), q2 = bfp(hv.z), q3 = bfp(hv.w);\
    a0 = fmaf(wA, q0.x, a0); a1 = fmaf(wA, q0.y, a1);                     \
    a2 = fmaf(wA, q1.x, a2); a3 = fmaf(wA, q1.y, a3);                     \
    a4 = fmaf(wA, q2.x, a4); a5 = fmaf(wA, q2.y, a5);                     \
    a6 = fmaf(wA, q3.x, a6); a7 = fmaf(wA, q3.y, a7);                     \
  }

__global__ __launch_bounds__(256) void agg2_g16(
    const unsigned short* __restrict__ Hb,
    const float2* __restrict__ as2, const float2* __restrict__ ad2,
    const int* __restrict__ row_start, const int* __restrict__ esrc,
    const float* __restrict__ b_mu, const float* __restrict__ b_ls,
    float* __restrict__ out_mu, float* __restrict__ out_ls, int N) {
  const int lane = threadIdx.x & 63;
  const int half = lane >> 5, sub = lane & 31;
  const int grp = (lane >> 4) & 1, li = lane & 15;
  const bool isMu = li < 8;
  const int g = (int)(blockIdx.x * 4 + (threadIdx.x >> 6));
  const int d = g * 2 + half;
  const bool dok = d < N;
  const int dc = dok ? d : N - 1;
  const float2 adv = ad2[dc];
  const float2 asv = as2[dc];
  const float wself_m = __expf(leaky02(asv.x + adv.x));
  const float wself_l = __expf(leaky02(asv.y + adv.y));
  float a0 = 0.f, a1 = 0.f, a2 = 0.f, a3 = 0.f, a4 = 0.f, a5 = 0.f, a6 = 0.f, a7 = 0.f;
  if (grp == 0) {
    const float wself = isMu ? wself_m : wself_l;
    uint4 sv = *(const uint4*)(Hb + (size_t)dc * 128 + li * 8);
    float2 q0 = bfp(sv.x), q1 = bfp(sv.y), q2 = bfp(sv.z), q3 = bfp(sv.w);
    a0 = wself * q0.x; a1 = wself * q0.y; a2 = wself * q1.x; a3 = wself * q1.y;
    a4 = wself * q2.x; a5 = wself * q2.y; a6 = wself * q3.x; a7 = wself * q3.y;
  }
  float den_m = (sub == 0) ? wself_m : 0.f;
  float den_l = (sub == 0) ? wself_l : 0.f;
  const int beg = row_start[dc];
  const int n = dok ? (row_start[dc + 1] - beg) : 0;
  const int nmax = max(n, __shfl_xor(n, 32));
  const int hbase = half * 32;
  for (int c0 = 0; c0 < nmax; c0 += 32) {
    int j = c0 + sub;
    bool v = j < n;
    int s = v ? esrc[beg + j] : 0;
    float wm = 0.f, wl = 0.f;
    if (v) {
      float2 av = as2[s];
      wm = __expf(leaky02(av.x + adv.x));
      wl = __expf(leaky02(av.y + adv.y));
    }
    den_m += wm;
    den_l += wl;
    int cnt = min(max(n - c0, 0), 32);
    int jj = 0;
    for (; jj + 8 <= cnt; jj += 8) { STEP2(jj) STEP2(jj + 2) STEP2(jj + 4) STEP2(jj + 6) }
    for (; jj < cnt; jj += 2) {
      int idx = jj + grp;
      int sA = __shfl(s, hbase + idx);
      float wmA = __shfl(wm, hbase + idx);
      float wlA = __shfl(wl, hbase + idx);
      float wA = isMu ? wmA : wlA;
      if (idx < cnt) {
        uint4 hv = *(const uint4*)(Hb + (size_t)sA * 128 + li * 8);
        float2 q0 = bfp(hv.x), q1 = bfp(hv.y), q2 = bfp(hv.z), q3 = bfp(hv.w);
        a0 = fmaf(wA, q0.x, a0); a1 = fmaf(wA, q0.y, a1);
        a2 = fmaf(wA, q1.x, a2); a3 = fmaf(wA, q1.y, a3);
        a4 = fmaf(wA, q2.x, a4); a5 = fmaf(wA, q2.y, a5);
        a6 = fmaf(wA, q3.x, a6); a7 = fmaf(wA, q3.y, a7);
      }
    }
  }
  a0 += __shfl_xor(a0, 16); a1 += __shfl_xor(a1, 16);
  a2 += __shfl_xor(a2, 16); a3 += __shfl_xor(a3, 16);
  a4 += __shfl_xor(a4, 16); a5 += __shfl_xor(a5, 16);
  a6 += __shfl_xor(a6, 16); a7 += __shfl_xor(a7, 16);
#pragma unroll
  for (int o = 16; o > 0; o >>= 1) {
    den_m += __shfl_xor(den_m, o);
    den_l += __shfl_xor(den_l, o);
  }
  if (dok && grp == 0) {
    float inv = isMu ? (1.0f / den_m) : (1.0f / den_l);
    const float* bp;
    float* op;
    if (isMu) { bp = b_mu + li * 8; op = out_mu + (size_t)d * 64 + li * 8; }
    else      { bp = b_ls + (li - 8) * 8; op = out_ls + (size_t)d * 64 + (li - 8) * 8; }
    float4 b0 = *(const float4*)bp;
    float4 b1 = *(const float4*)(bp + 4);
    float4 o0, o1;
    o0.x = fmaf(a0, inv, b0.x); o0.y = fmaf(a1, inv, b0.y);
    o0.z = fmaf(a2, inv, b0.z); o0.w = fmaf(a3, inv, b0.w);
    o1.x = fmaf(a4, inv, b1.x); o1.y = fmaf(a5, inv, b1.y);
    o1.z = fmaf(a6, inv, b1.z); o1.w = fmaf(a7, inv, b1.w);
    *(float4*)op = o0;
    *(float4*)(op + 4) = o1;
  }
}

// ---------------- launch ----------------

extern "C" void kernel_launch(void* const* d_in, const int* in_sizes, int n_in,
                              void* d_out, int out_size, void* d_ws, size_t ws_size,
                              hipStream_t stream) {
  const float* x = (const float*)d_in[0];
  const int* ei = (const int*)d_in[1];
  const float* W1 = (const float*)d_in[2];
  const float* a_src1 = (const float*)d_in[3];
  const float* a_dst1 = (const float*)d_in[4];
  const float* b1 = (const float*)d_in[5];
  const float* W_mu = (const float*)d_in[6];
  const float* a_src_mu = (const float*)d_in[7];
  const float* a_dst_mu = (const float*)d_in[8];
  const float* b_mu = (const float*)d_in[9];
  const float* W_ls = (const float*)d_in[10];
  const float* a_src_ls = (const float*)d_in[11];
  const float* a_dst_ls = (const float*)d_in[12];
  const float* b_ls = (const float*)d_in[13];

  const int N = in_sizes[0] / 128;  // 50000
  const int E = in_sizes[1] / 2;    // 800000
  const int NBUCK = (N + BDSTS - 1) >> BSHIFT;  // 196 (<=256)

  uint8_t* p = (uint8_t*)d_ws;
  auto carve = [&](size_t bytes) -> void* {
    void* q = (void*)p;
    p += (bytes + 255) & ~(size_t)255;
    return q;
  };
  int* bcount = (int*)carve((size_t)(NBUCK + 2) * 4);  // bcount[0..NBUCK], done at NBUCK+1
  int* done = bcount + NBUCK + 1;
  int* bstart = (int*)carve((size_t)(NBUCK + 1) * 4);
  int* bcursor = (int*)carve((size_t)NBUCK * 4);
  int* row_start = (int*)carve((size_t)(N + 1) * 4);
  int* esrc = (int*)carve((size_t)E * 4);
  unsigned* pairs = (unsigned*)carve((size_t)E * 4);
  unsigned short* Hb1 = (unsigned short*)carve((size_t)N * 128 * 2);  // bf16; reused as Hb2
  _Float16* h1 = (_Float16*)carve((size_t)N * 128 * 2);               // fp16 gemm2 input
  _Float16* Wt1 = (_Float16*)carve((size_t)128 * 128 * 2);
  _Float16* Wt2 = (_Float16*)carve((size_t)128 * 128 * 2);
  float* as1 = (float*)carve((size_t)N * 4);
  float* ad1 = (float*)carve((size_t)N * 4);
  float* as2 = (float*)carve((size_t)N * 8);
  float* ad2 = (float*)carve((size_t)N * 8);

  unsigned short* Hb2 = Hb1;

  hipMemsetAsync(bcount, 0, (size_t)(NBUCK + 2) * 4, stream);

  const int nPB = 64;                     // prep blocks
  const int nHB = (E + 2047) / 2048;      // hist blocks
  prep_hist<<<nPB + nHB, 256, 0, stream>>>(W1, W_mu, W_ls, Wt1, Wt2,
                                           ei, bcount, E, nPB, nHB,
                                           bstart, bcursor, row_start, done, NBUCK, N);

  const int nGB = (N + 63) / 64;          // gemm1 blocks
  const int nSC = (E + CHUNK - 1) / CHUNK;  // scatter blocks
  gemm1_scatter<<<nGB + nSC, 256, 0, stream>>>(x, Wt1, a_src1, a_dst1, Hb1, as1, ad1, N,
                                               ei, bcursor, pairs, E, nGB);
  fine_kernel<<<NBUCK, 256, 0, stream>>>(pairs, bstart, row_start, esrc, N);

  const int nwaves = (N + 1) / 2;
  const int nblk = (nwaves + 3) / 4;
  agg1_g16<<<nblk, 256, 0, stream>>>(Hb1, as1, ad1, row_start, esrc, b1, h1, N);
  gemm2_mfma<<<(N + 63) / 64, 256, 0, stream>>>(h1, Wt2, a_src_mu, a_dst_mu,
                                                a_src_ls, a_dst_ls, Hb2, as2, ad2, N);
  float* out_mu = (float*)d_out;
  float* out_ls = out_mu + (size_t)N * 64;
  agg2_g16<<<nblk, 256, 0, stream>>>(Hb2, (const float2*)as2, (const float2*)ad2,
                                     row_start, esrc, b_mu, b_ls, out_mu, out_ls, N);
}